// Round 8
// baseline (3108.403 us; speedup 1.0000x reference)
//
#include <hip/hip_runtime.h>

// Problem constants: T=512, N=512, I=256, H=256
#define kT 512
#define kN 512
#define kH 256
#define SBL 128  // scan blocks
#define SQ 4     // seqs per scan block

typedef float  f32x4  __attribute__((ext_vector_type(4)));
typedef __bf16 bf16x8 __attribute__((ext_vector_type(8)));
typedef __bf16 bf16x4 __attribute__((ext_vector_type(4)));
typedef __bf16 bf16x2 __attribute__((ext_vector_type(2)));

static __device__ __forceinline__ float sigm(float x) {
  float e = __builtin_amdgcn_exp2f(-1.4426950408889634f * x);
  return __builtin_amdgcn_rcpf(1.0f + e);
}
static __device__ __forceinline__ float tanh_fast(float x) {
  float e = __builtin_amdgcn_exp2f(-2.8853900817779268f * x);
  return fmaf(2.0f, __builtin_amdgcn_rcpf(1.0f + e), -1.0f);
}

// ---------------------------------------------------------------------------
// Phase 1: gi = x @ W_ih^T + b_ih (+ b_hh for r,z), bf16, layout v4
// ("reader-owns-chunk"): per (t, blk4 = seq>>2, w2) one contiguous 768-B
// chunk = 384 bf16:  chunk[(g*2+tp)*64 + c*4 + i] =
//   gi[seq = blk4*4 + i][col = g*256 + w2*32 + tp*16 + c]
// chunk base (elements) = ((t*128 + blk4)*8 + w2)*384
// Verified by element trace: (t=0,s=5,j=300) -> phase1 dest 3633 == scan read.
// ---------------------------------------------------------------------------
__global__ __launch_bounds__(512) void gi_gemm(
    const float* __restrict__ x, const float* __restrict__ Wih,
    const float* __restrict__ bih, const float* __restrict__ bhh,
    __bf16* __restrict__ gis)
{
  __shared__ __align__(16) __bf16 Al[128][264];
  __shared__ __align__(16) __bf16 Bl[128][264];
  const int tid  = threadIdx.x;
  const int lane = tid & 63, w = tid >> 6;
  const int wm = w & 1, wn = w >> 1;            // 2 x 4 wave grid
  const int c = lane & 15, lg = lane >> 4;
  const long R0 = (long)blockIdx.x * 128;
  const int t  = (int)(R0 >> 9);
  const int n0 = (int)(R0 & 511);

  #pragma unroll
  for (int it = 0; it < 16; ++it) {
    int slot = tid + it * 512;
    int r  = slot >> 6;
    int kq = (slot & 63) * 4;
    float4 av = *(const float4*)(x + (R0 + r) * 256 + kq);
    bf16x4 a4 = {(__bf16)av.x, (__bf16)av.y, (__bf16)av.z, (__bf16)av.w};
    *(bf16x4*)(&Al[r][kq]) = a4;
  }

  for (int nb = 0; nb < 6; ++nb) {
    __syncthreads();
    #pragma unroll
    for (int it = 0; it < 16; ++it) {
      int slot = tid + it * 512;
      int r  = slot >> 6;
      int kq = (slot & 63) * 4;
      float4 bv = *(const float4*)(Wih + (long)(nb * 128 + r) * 256 + kq);
      bf16x4 b4 = {(__bf16)bv.x, (__bf16)bv.y, (__bf16)bv.z, (__bf16)bv.w};
      *(bf16x4*)(&Bl[r][kq]) = b4;
    }
    __syncthreads();

    const int gate = nb >> 1;
    f32x4 acc[4][2];
    #pragma unroll
    for (int nt = 0; nt < 2; ++nt) {
      int j = nb * 128 + wn * 32 + nt * 16 + c;
      float bv = bih[j] + (gate < 2 ? bhh[j] : 0.0f);
      #pragma unroll
      for (int mt = 0; mt < 4; ++mt) acc[mt][nt] = (f32x4){bv, bv, bv, bv};
    }

    #pragma unroll
    for (int ss = 0; ss < 8; ++ss) {
      bf16x8 af[4], bfr[2];
      #pragma unroll
      for (int mt = 0; mt < 4; ++mt)
        af[mt] = *(const bf16x8*)(&Al[wm * 64 + mt * 16 + c][ss * 32 + lg * 8]);
      #pragma unroll
      for (int nt = 0; nt < 2; ++nt)
        bfr[nt] = *(const bf16x8*)(&Bl[wn * 32 + nt * 16 + c][ss * 32 + lg * 8]);
      #pragma unroll
      for (int mt = 0; mt < 4; ++mt)
        #pragma unroll
        for (int nt = 0; nt < 2; ++nt)
          acc[mt][nt] = __builtin_amdgcn_mfma_f32_16x16x32_bf16(af[mt], bfr[nt], acc[mt][nt], 0, 0, 0);
    }

    // Epilogue v4: one bf16x4 (8 B) store per (mt, nt)
    const int w2g = (nb & 1) * 4 + wn;
    #pragma unroll
    for (int mt = 0; mt < 4; ++mt) {
      const int S16 = n0 + wm * 64 + mt * 16;
      const long blk4 = (S16 >> 2) + lg;
      #pragma unroll
      for (int nt = 0; nt < 2; ++nt) {
        bf16x4 v;
        #pragma unroll
        for (int i = 0; i < 4; ++i) v[i] = (__bf16)acc[mt][nt][i];
        long dest = (((long)t * 128 + blk4) * 8 + w2g) * 384 +
                    (gate * 2 + nt) * 64 + c * 4;
        *(bf16x4*)(gis + dest) = v;
      }
    }
  }
}

// ---------------------------------------------------------------------------
// Phase 2: scan. 128 blocks x 512 thr (8 waves, 2/SIMD). W_hh pinned to
// EXACTLY 128 AGPRs/wave: n bf16 (64) + z fp8 (32) + r fp8 (32); acc arch.
// h in 2KB bf16 LDS + 1KB fp8 LDS (XOR swz), double-buffered.
// gi: REGISTER prefetch (6 x 8B loads/lane, one step ahead) -- no LDS DMA,
// no manual vmcnt; loads stay in flight across the raw s_barrier.
// ---------------------------------------------------------------------------
__global__ __attribute__((amdgpu_waves_per_eu(2, 2))) __launch_bounds__(512)
void gru_scan(
    const __bf16* __restrict__ gis, const float* __restrict__ h0,
    const float* __restrict__ done, const float* __restrict__ Whh,
    const float* __restrict__ bhh, float* __restrict__ out)
{
  __shared__ __align__(16) __bf16 hbuf[2][SQ * 256];          // 4 KB
  __shared__ __align__(16) unsigned char h8buf[2][SQ * 256];  // 2 KB
  __shared__ unsigned char doneL[kT * SQ];                    // 2 KB

  const int tid  = threadIdx.x;
  const int lane = tid & 63, w2 = tid >> 6;
  const int b   = blockIdx.x;
  const int nb4 = b * SQ;
  const int c = lane & 15, lg = lane >> 4;
  const int jh0 = w2 * 32 + c, jh1 = jh0 + 16;
  const int sr = c & 3;                  // dup row for M=4

  // --- W_hh -> exactly 128 AGPRs: n bf16x8 (4r), z fp8 (2r), r fp8 (2r)
  f32x4 wfn[16];
  long  wfz[16], wfr[16];
  #pragma unroll
  for (int tp = 0; tp < 2; ++tp) {
    const int jn = 512 + w2 * 32 + tp * 16 + c;
    const int jz = 256 + w2 * 32 + tp * 16 + c;
    const int jr =       w2 * 32 + tp * 16 + c;
    #pragma unroll
    for (int ss = 0; ss < 8; ++ss) {
      const int k0 = ss * 32 + lg * 8;
      float4 n0_ = *(const float4*)(Whh + (long)jn * 256 + k0);
      float4 n1_ = *(const float4*)(Whh + (long)jn * 256 + k0 + 4);
      bf16x8 vn = {(__bf16)n0_.x, (__bf16)n0_.y, (__bf16)n0_.z, (__bf16)n0_.w,
                   (__bf16)n1_.x, (__bf16)n1_.y, (__bf16)n1_.z, (__bf16)n1_.w};
      wfn[tp * 8 + ss] = __builtin_bit_cast(f32x4, vn);
      float4 z0 = *(const float4*)(Whh + (long)jz * 256 + k0);
      float4 z1 = *(const float4*)(Whh + (long)jz * 256 + k0 + 4);
      int zl = __builtin_amdgcn_cvt_pk_fp8_f32(z0.x, z0.y, 0, 0);
      zl     = __builtin_amdgcn_cvt_pk_fp8_f32(z0.z, z0.w, zl, 1);
      int zh = __builtin_amdgcn_cvt_pk_fp8_f32(z1.x, z1.y, 0, 0);
      zh     = __builtin_amdgcn_cvt_pk_fp8_f32(z1.z, z1.w, zh, 1);
      int2 zp = {zl, zh};
      wfz[tp * 8 + ss] = __builtin_bit_cast(long, zp);
      float4 r0_ = *(const float4*)(Whh + (long)jr * 256 + k0);
      float4 r1_ = *(const float4*)(Whh + (long)jr * 256 + k0 + 4);
      int rl = __builtin_amdgcn_cvt_pk_fp8_f32(r0_.x, r0_.y, 0, 0);
      rl     = __builtin_amdgcn_cvt_pk_fp8_f32(r0_.z, r0_.w, rl, 1);
      int rh = __builtin_amdgcn_cvt_pk_fp8_f32(r1_.x, r1_.y, 0, 0);
      rh     = __builtin_amdgcn_cvt_pk_fp8_f32(r1_.z, r1_.w, rh, 1);
      int2 rp = {rl, rh};
      wfr[tp * 8 + ss] = __builtin_bit_cast(long, rp);
    }
  }
  #pragma unroll
  for (int i = 0; i < 16; ++i) {
    asm volatile("" : "+a"(wfn[i]));
    asm volatile("" : "+a"(wfz[i]));
    asm volatile("" : "+a"(wfr[i]));
  }
  const float bn0 = bhh[512 + jh0];
  const float bn1 = bhh[512 + jh1];

  // --- done -> LDS, shifted (row t = done[t+1]; last row 0)
  for (int idx = tid; idx < (kT - 1) * SQ; idx += 512) {
    int tt = idx >> 2, s = idx & 3;
    doneL[idx] = (unsigned char)(done[(long)(tt + 1) * kN + nb4 + s] != 0.0f);
  }
  if (tid < SQ) doneL[(kT - 1) * SQ + tid] = 0;

  // --- h init (scaled by 1-done[0]) into hbuf[0] + h8buf[0] + hold regs
  {
    const int s  = tid >> 7;            // 0..3
    const int k2 = (tid & 127) * 2;     // 0..254
    float sc = 1.0f - done[nb4 + s];
    const float* hp = h0 + (long)(nb4 + s) * 256 + k2;
    float f0 = hp[0] * sc, f1 = hp[1] * sc;
    bf16x2 v = {(__bf16)f0, (__bf16)f1};
    *(bf16x2*)(&hbuf[0][s * 256 + (((k2 * 2) ^ (s << 4)) >> 1)]) = v;
    int pk = __builtin_amdgcn_cvt_pk_fp8_f32(f0, f1, 0, 0);
    *(unsigned short*)(&h8buf[0][s * 256 + (k2 ^ (s << 3))]) = (unsigned short)(pk & 0xffff);
  }
  float hold[4][2];
  #pragma unroll
  for (int i = 0; i < 4; ++i) {
    float sc = 1.0f - done[nb4 + i];
    hold[i][0] = h0[(long)(nb4 + i) * 256 + jh0] * sc;
    hold[i][1] = h0[(long)(nb4 + i) * 256 + jh1] * sc;
  }
  __syncthreads();

  // --- gi register prefetch: this (b, w2, c)'s chunk slice, one step ahead
  const long cstep = 128L * 8 * 384;                       // per-t chunk stride
  const __bf16* gcb = gis + ((long)b * 8 + w2) * 384 + c * 4;
  bf16x4 p00 = *(const bf16x4*)(gcb);
  bf16x4 p01 = *(const bf16x4*)(gcb + 64);
  bf16x4 p10 = *(const bf16x4*)(gcb + 128);
  bf16x4 p11 = *(const bf16x4*)(gcb + 192);
  bf16x4 pn0 = *(const bf16x4*)(gcb + 256);
  bf16x4 pn1 = *(const bf16x4*)(gcb + 320);

  #pragma unroll 1
  for (int t = 0; t < kT; ++t) {
    // keep W resident in AGPRs across the loop body
    #pragma unroll
    for (int i = 0; i < 16; ++i) {
      asm volatile("" : "+a"(wfn[i]));
      asm volatile("" : "+a"(wfz[i]));
      asm volatile("" : "+a"(wfr[i]));
    }

    // (A) consume prefetched gi(t)
    bf16x4 q00 = p00, q01 = p01, q10 = p10, q11 = p11, qn0 = pn0, qn1 = pn1;
    unsigned du = *(const unsigned*)(&doneL[t * SQ]);

    // (B) issue gi(t+1) loads (clamped at tail; latency spans MFMA+gates+barrier)
    {
      const long tn = (t < kT - 1) ? (t + 1) : t;
      const __bf16* gc = gcb + tn * cstep;
      p00 = *(const bf16x4*)(gc);
      p01 = *(const bf16x4*)(gc + 64);
      p10 = *(const bf16x4*)(gc + 128);
      p11 = *(const bf16x4*)(gc + 192);
      pn0 = *(const bf16x4*)(gc + 256);
      pn1 = *(const bf16x4*)(gc + 320);
    }

    f32x4 ar0, ar1, az0, az1, an0, an1;
    #pragma unroll
    for (int i = 0; i < 4; ++i) {
      ar0[i] = (float)q00[i]; ar1[i] = (float)q01[i];
      az0[i] = (float)q10[i]; az1[i] = (float)q11[i];
    }
    an0 = (f32x4){bn0, bn0, bn0, bn0};
    an1 = (f32x4){bn1, bn1, bn1, bn1};

    // (C) MFMA over K=256: A = h rows dup'd (sr), B = AGPR-resident W
    {
      const __bf16* hb = &hbuf[t & 1][0];
      const unsigned char* h8b = &h8buf[t & 1][0];
      #pragma unroll
      for (int ss = 0; ss < 8; ++ss) {
        int cb = (ss * 64 + lg * 16) ^ (sr << 4);
        bf16x8 afr = *(const bf16x8*)(hb + sr * 256 + (cb >> 1));
        long   a8  = *(const long*)(h8b + sr * 256 + ((ss * 32 + lg * 8) ^ (sr << 3)));
        ar0 = __builtin_amdgcn_mfma_f32_16x16x32_fp8_fp8(a8, wfr[ss],     ar0, 0, 0, 0);
        ar1 = __builtin_amdgcn_mfma_f32_16x16x32_fp8_fp8(a8, wfr[8 + ss], ar1, 0, 0, 0);
        az0 = __builtin_amdgcn_mfma_f32_16x16x32_fp8_fp8(a8, wfz[ss],     az0, 0, 0, 0);
        az1 = __builtin_amdgcn_mfma_f32_16x16x32_fp8_fp8(a8, wfz[8 + ss], az1, 0, 0, 0);
        an0 = __builtin_amdgcn_mfma_f32_16x16x32_bf16(afr, __builtin_bit_cast(bf16x8, wfn[ss]),     an0, 0, 0, 0);
        an1 = __builtin_amdgcn_mfma_f32_16x16x32_bf16(afr, __builtin_bit_cast(bf16x8, wfn[8 + ss]), an1, 0, 0, 0);
      }
    }

    // (D) gates + update + stores (rows 0..3 real; lg==0 lanes store)
    {
      float* op = out + ((long)t * kN + nb4) * kH;
      __bf16* hw = &hbuf[(t & 1) ^ 1][0];
      unsigned char* h8w = &h8buf[(t & 1) ^ 1][0];
      #pragma unroll
      for (int i = 0; i < 4; ++i) {
        const float dn = (float)((du >> (8 * i)) & 255u);
        float r0 = sigm(ar0[i]);
        float r1 = sigm(ar1[i]);
        float z0 = sigm(az0[i]);
        float z1 = sigm(az1[i]);
        float n0v = tanh_fast((float)qn0[i] + r0 * an0[i]);
        float n1v = tanh_fast((float)qn1[i] + r1 * an1[i]);
        float hn0 = n0v + z0 * (hold[i][0] - n0v);
        float hn1 = n1v + z1 * (hold[i][1] - n1v);
        float hk0 = hn0 * (1.0f - dn);
        float hk1 = hn1 * (1.0f - dn);
        hold[i][0] = hk0;
        hold[i][1] = hk1;
        if (lg == 0) {
          op[(long)i * kH + jh0] = hn0;
          op[(long)i * kH + jh1] = hn1;
          hw[(i * 512 + ((jh0 * 2) ^ (i << 4))) >> 1] = (__bf16)hk0;
          hw[(i * 512 + ((jh1 * 2) ^ (i << 4))) >> 1] = (__bf16)hk1;
          int pk8 = __builtin_amdgcn_cvt_pk_fp8_f32(hk0, hk1, 0, 0);
          h8w[i * 256 + (jh0 ^ (i << 3))] = (unsigned char)(pk8 & 255);
          h8w[i * 256 + (jh1 ^ (i << 3))] = (unsigned char)((pk8 >> 8) & 255);
        }
      }
    }

    // (E) h(t+1) visible to all waves; gi prefetch loads stay in flight
    // (raw s_barrier does NOT drain vmcnt; lgkmcnt(0) covers the ds_writes).
    asm volatile("s_waitcnt lgkmcnt(0)" ::: "memory");
    asm volatile("s_barrier" ::: "memory");
    __builtin_amdgcn_sched_barrier(0);
  }

  // final hidden state (doneL last row = 0, so hold == h_T)
  if (lg == 0) {
    float* outF = out + (long)kT * kN * kH;
    #pragma unroll
    for (int i = 0; i < 4; ++i) {
      outF[(long)(nb4 + i) * kH + jh0] = hold[i][0];
      outF[(long)(nb4 + i) * kH + jh1] = hold[i][1];
    }
  }
}

// ---------------------------------------------------------------------------
// Fallback (ws too small): naive fp32.
// ---------------------------------------------------------------------------
__global__ __launch_bounds__(256) void gru_naive(
    const float* __restrict__ x, const float* __restrict__ h0,
    const float* __restrict__ done, const float* __restrict__ Wih,
    const float* __restrict__ Whh, const float* __restrict__ bih,
    const float* __restrict__ bhh, float* __restrict__ out)
{
  __shared__ float hsA[16][257];
  __shared__ float hsB[16][257];
  const int tid = threadIdx.x;
  const int b = blockIdx.x, nb = b * 16;
  for (int s = 0; s < 16; ++s)
    hsA[s][tid] = h0[(long)(nb + s) * 256 + tid] * (1.0f - done[nb + s]);
  __syncthreads();
  float (*hr)[257] = hsA;
  float (*hw)[257] = hsB;
  float* outF = out + (long)kT * kN * kH;
  for (int t = 0; t < kT; ++t) {
    for (int s = 0; s < 16; ++s) {
      const float* xr = x + ((long)t * kN + nb + s) * 256;
      float pr  = bih[tid] + bhh[tid];
      float pz  = bih[256 + tid] + bhh[256 + tid];
      float pnx = bih[512 + tid];
      float pnh = bhh[512 + tid];
      const float* wr = Wih + (long)tid * 256;
      const float* wz = Wih + (long)(256 + tid) * 256;
      const float* wn = Wih + (long)(512 + tid) * 256;
      const float* vr = Whh + (long)tid * 256;
      const float* vz = Whh + (long)(256 + tid) * 256;
      const float* vn = Whh + (long)(512 + tid) * 256;
      #pragma unroll 4
      for (int k = 0; k < 256; ++k) {
        float xv = xr[k], hv = hr[s][k];
        pr  = fmaf(xv, wr[k], pr);  pr  = fmaf(hv, vr[k], pr);
        pz  = fmaf(xv, wz[k], pz);  pz  = fmaf(hv, vz[k], pz);
        pnx = fmaf(xv, wn[k], pnx); pnh = fmaf(hv, vn[k], pnh);
      }
      float r = sigm(pr), z = sigm(pz);
      float n = tanh_fast(pnx + r * pnh);
      float ho = hr[s][tid];
      float hn = n + z * (ho - n);
      out[((long)t * kN + nb + s) * 256 + tid] = hn;
      if (t == kT - 1) outF[(long)(nb + s) * 256 + tid] = hn;
      float d = (t < kT - 1) ? done[(long)(t + 1) * kN + nb + s] : 0.0f;
      hw[s][tid] = hn * (1.0f - d);
    }
    __syncthreads();
    float (*tmp)[257] = hr; hr = hw; hw = tmp;
  }
}

extern "C" void kernel_launch(void* const* d_in, const int* in_sizes, int n_in,
                              void* d_out, int out_size, void* d_ws, size_t ws_size,
                              hipStream_t stream) {
  const float* x    = (const float*)d_in[0];
  const float* h0   = (const float*)d_in[1];
  const float* done = (const float*)d_in[2];
  const float* Wih  = (const float*)d_in[3];
  const float* Whh  = (const float*)d_in[4];
  const float* bih  = (const float*)d_in[5];
  const float* bhh  = (const float*)d_in[6];
  float* out = (float*)d_out;

  const size_t GI_BYTES = (size_t)kT * kN * 768 * 2;  // 402.7 MB bf16
  if (ws_size >= GI_BYTES) {
    __bf16* gis = (__bf16*)d_ws;
    hipLaunchKernelGGL(gi_gemm, dim3(2048), dim3(512), 0, stream, x, Wih, bih, bhh, gis);
    hipLaunchKernelGGL(gru_scan, dim3(SBL), dim3(512), 0, stream, gis, h0, done, Whh, bhh, out);
  } else {
    hipLaunchKernelGGL(gru_naive, dim3(32), dim3(256), 0, stream, x, h0, done, Wih, Whh, bih, bhh, out);
  }
}

// Round 9
// 1290.194 us; speedup vs baseline: 2.4093x; 2.4093x over previous
//
#include <hip/hip_runtime.h>

// Problem constants: T=512, N=512, I=256, H=256
#define kT 512
#define kN 512
#define kH 256
#define SBL 128  // scan blocks
#define SQ 4     // seqs per scan block

typedef float  f32x4  __attribute__((ext_vector_type(4)));
typedef __bf16 bf16x8 __attribute__((ext_vector_type(8)));
typedef __bf16 bf16x4 __attribute__((ext_vector_type(4)));
typedef __bf16 bf16x2 __attribute__((ext_vector_type(2)));

static __device__ __forceinline__ float sigm(float x) {
  float e = __builtin_amdgcn_exp2f(-1.4426950408889634f * x);
  return __builtin_amdgcn_rcpf(1.0f + e);
}
static __device__ __forceinline__ float tanh_fast(float x) {
  float e = __builtin_amdgcn_exp2f(-2.8853900817779268f * x);
  return fmaf(2.0f, __builtin_amdgcn_rcpf(1.0f + e), -1.0f);
}

// ---------------------------------------------------------------------------
// Phase 1: gi = x @ W_ih^T + b_ih (+ b_hh for r,z), bf16, layout v4
// ("reader-owns-chunk"): per (t, blk4 = seq>>2, w2) one contiguous 768-B
// chunk = 384 bf16:  chunk[(g*2+tp)*64 + c*4 + i] =
//   gi[seq = blk4*4 + i][col = g*256 + w2*32 + tp*16 + c]
// chunk base (elements) = ((t*128 + blk4)*8 + w2)*384
// Validated end-to-end in round 8 (passed with this exact layout).
// ---------------------------------------------------------------------------
__global__ __launch_bounds__(512) void gi_gemm(
    const float* __restrict__ x, const float* __restrict__ Wih,
    const float* __restrict__ bih, const float* __restrict__ bhh,
    __bf16* __restrict__ gis)
{
  __shared__ __align__(16) __bf16 Al[128][264];
  __shared__ __align__(16) __bf16 Bl[128][264];
  const int tid  = threadIdx.x;
  const int lane = tid & 63, w = tid >> 6;
  const int wm = w & 1, wn = w >> 1;            // 2 x 4 wave grid
  const int c = lane & 15, lg = lane >> 4;
  const long R0 = (long)blockIdx.x * 128;
  const int t  = (int)(R0 >> 9);
  const int n0 = (int)(R0 & 511);

  #pragma unroll
  for (int it = 0; it < 16; ++it) {
    int slot = tid + it * 512;
    int r  = slot >> 6;
    int kq = (slot & 63) * 4;
    float4 av = *(const float4*)(x + (R0 + r) * 256 + kq);
    bf16x4 a4 = {(__bf16)av.x, (__bf16)av.y, (__bf16)av.z, (__bf16)av.w};
    *(bf16x4*)(&Al[r][kq]) = a4;
  }

  for (int nb = 0; nb < 6; ++nb) {
    __syncthreads();
    #pragma unroll
    for (int it = 0; it < 16; ++it) {
      int slot = tid + it * 512;
      int r  = slot >> 6;
      int kq = (slot & 63) * 4;
      float4 bv = *(const float4*)(Wih + (long)(nb * 128 + r) * 256 + kq);
      bf16x4 b4 = {(__bf16)bv.x, (__bf16)bv.y, (__bf16)bv.z, (__bf16)bv.w};
      *(bf16x4*)(&Bl[r][kq]) = b4;
    }
    __syncthreads();

    const int gate = nb >> 1;
    f32x4 acc[4][2];
    #pragma unroll
    for (int nt = 0; nt < 2; ++nt) {
      int j = nb * 128 + wn * 32 + nt * 16 + c;
      float bv = bih[j] + (gate < 2 ? bhh[j] : 0.0f);
      #pragma unroll
      for (int mt = 0; mt < 4; ++mt) acc[mt][nt] = (f32x4){bv, bv, bv, bv};
    }

    #pragma unroll
    for (int ss = 0; ss < 8; ++ss) {
      bf16x8 af[4], bfr[2];
      #pragma unroll
      for (int mt = 0; mt < 4; ++mt)
        af[mt] = *(const bf16x8*)(&Al[wm * 64 + mt * 16 + c][ss * 32 + lg * 8]);
      #pragma unroll
      for (int nt = 0; nt < 2; ++nt)
        bfr[nt] = *(const bf16x8*)(&Bl[wn * 32 + nt * 16 + c][ss * 32 + lg * 8]);
      #pragma unroll
      for (int mt = 0; mt < 4; ++mt)
        #pragma unroll
        for (int nt = 0; nt < 2; ++nt)
          acc[mt][nt] = __builtin_amdgcn_mfma_f32_16x16x32_bf16(af[mt], bfr[nt], acc[mt][nt], 0, 0, 0);
    }

    // Epilogue v4: one bf16x4 (8 B) store per (mt, nt)
    const int w2g = (nb & 1) * 4 + wn;
    #pragma unroll
    for (int mt = 0; mt < 4; ++mt) {
      const int S16 = n0 + wm * 64 + mt * 16;
      const long blk4 = (S16 >> 2) + lg;
      #pragma unroll
      for (int nt = 0; nt < 2; ++nt) {
        bf16x4 v;
        #pragma unroll
        for (int i = 0; i < 4; ++i) v[i] = (__bf16)acc[mt][nt][i];
        long dest = (((long)t * 128 + blk4) * 8 + w2g) * 384 +
                    (gate * 2 + nt) * 64 + c * 4;
        *(bf16x4*)(gis + dest) = v;
      }
    }
  }
}

// ---------------------------------------------------------------------------
// Phase 2: scan. 128 blocks x 512 thr (8 waves, 2/SIMD). Register budget
// made to fit PROVABLY: AGPR = exactly 128 (wfn + wfz bf16, pinned once);
// MFMA accs pinned "+v" (arch side, 24 regs); r-gate W as fp8 in LDS
// (64 KB, each thread reads back its own 8-B fragment -- conflict-free).
// z,n numerics bf16 (accuracy); r fp8 (round-5-validated, absmax 0.019).
// gi: register prefetch one step ahead; plain __syncthreads() per step.
// ---------------------------------------------------------------------------
__global__ __attribute__((amdgpu_waves_per_eu(2, 2))) __launch_bounds__(512)
void gru_scan(
    const __bf16* __restrict__ gis, const float* __restrict__ h0,
    const float* __restrict__ done, const float* __restrict__ Whh,
    const float* __restrict__ bhh, float* __restrict__ out)
{
  __shared__ __align__(16) __bf16 hbuf[2][SQ * 256];          // 4 KB
  __shared__ __align__(16) unsigned char h8buf[2][SQ * 256];  // 2 KB
  __shared__ __align__(16) unsigned char wr8[8 * 16 * 64 * 8];// 64 KB
  __shared__ unsigned char doneL[kT * SQ];                    // 2 KB

  const int tid  = threadIdx.x;
  const int lane = tid & 63, w2 = tid >> 6;
  const int b   = blockIdx.x;
  const int nb4 = b * SQ;
  const int c = lane & 15, lg = lane >> 4;
  const int jh0 = w2 * 32 + c, jh1 = jh0 + 16;
  const int sr = c & 3;                  // dup row for M=4

  // --- W_hh: n,z bf16 -> 128 AGPRs (pinned once); r fp8 -> LDS (own slot)
  f32x4 wfn[16], wfz[16];
  #pragma unroll
  for (int tp = 0; tp < 2; ++tp) {
    const int jn = 512 + w2 * 32 + tp * 16 + c;
    const int jz = 256 + w2 * 32 + tp * 16 + c;
    const int jr =       w2 * 32 + tp * 16 + c;
    #pragma unroll
    for (int ss = 0; ss < 8; ++ss) {
      const int k0 = ss * 32 + lg * 8;
      float4 n0_ = *(const float4*)(Whh + (long)jn * 256 + k0);
      float4 n1_ = *(const float4*)(Whh + (long)jn * 256 + k0 + 4);
      bf16x8 vn = {(__bf16)n0_.x, (__bf16)n0_.y, (__bf16)n0_.z, (__bf16)n0_.w,
                   (__bf16)n1_.x, (__bf16)n1_.y, (__bf16)n1_.z, (__bf16)n1_.w};
      wfn[tp * 8 + ss] = __builtin_bit_cast(f32x4, vn);
      float4 z0 = *(const float4*)(Whh + (long)jz * 256 + k0);
      float4 z1 = *(const float4*)(Whh + (long)jz * 256 + k0 + 4);
      bf16x8 vz = {(__bf16)z0.x, (__bf16)z0.y, (__bf16)z0.z, (__bf16)z0.w,
                   (__bf16)z1.x, (__bf16)z1.y, (__bf16)z1.z, (__bf16)z1.w};
      wfz[tp * 8 + ss] = __builtin_bit_cast(f32x4, vz);
      float4 r0_ = *(const float4*)(Whh + (long)jr * 256 + k0);
      float4 r1_ = *(const float4*)(Whh + (long)jr * 256 + k0 + 4);
      int rl = __builtin_amdgcn_cvt_pk_fp8_f32(r0_.x, r0_.y, 0, 0);
      rl     = __builtin_amdgcn_cvt_pk_fp8_f32(r0_.z, r0_.w, rl, 1);
      int rh = __builtin_amdgcn_cvt_pk_fp8_f32(r1_.x, r1_.y, 0, 0);
      rh     = __builtin_amdgcn_cvt_pk_fp8_f32(r1_.z, r1_.w, rh, 1);
      int2 rp = {rl, rh};
      // LDS slot: ((w2*16 + tp*8 + ss)*64 + lane)*8 -- read back by same thread
      *(int2*)(&wr8[(((w2 * 16 + tp * 8 + ss) * 64) + lane) * 8]) = rp;
    }
  }
  #pragma unroll
  for (int i = 0; i < 16; ++i) {
    asm volatile("" : "+a"(wfn[i]));
    asm volatile("" : "+a"(wfz[i]));
  }
  const float bn0 = bhh[512 + jh0];
  const float bn1 = bhh[512 + jh1];

  // --- done -> LDS, shifted (row t = done[t+1]; last row 0)
  for (int idx = tid; idx < (kT - 1) * SQ; idx += 512) {
    int tt = idx >> 2, s = idx & 3;
    doneL[idx] = (unsigned char)(done[(long)(tt + 1) * kN + nb4 + s] != 0.0f);
  }
  if (tid < SQ) doneL[(kT - 1) * SQ + tid] = 0;

  // --- h init (scaled by 1-done[0]) into hbuf[0] + h8buf[0] + hold regs
  {
    const int s  = tid >> 7;            // 0..3
    const int k2 = (tid & 127) * 2;     // 0..254
    float sc = 1.0f - done[nb4 + s];
    const float* hp = h0 + (long)(nb4 + s) * 256 + k2;
    float f0 = hp[0] * sc, f1 = hp[1] * sc;
    bf16x2 v = {(__bf16)f0, (__bf16)f1};
    *(bf16x2*)(&hbuf[0][s * 256 + (((k2 * 2) ^ (s << 4)) >> 1)]) = v;
    int pk = __builtin_amdgcn_cvt_pk_fp8_f32(f0, f1, 0, 0);
    *(unsigned short*)(&h8buf[0][s * 256 + (k2 ^ (s << 3))]) = (unsigned short)(pk & 0xffff);
  }
  float hold[4][2];
  #pragma unroll
  for (int i = 0; i < 4; ++i) {
    float sc = 1.0f - done[nb4 + i];
    hold[i][0] = h0[(long)(nb4 + i) * 256 + jh0] * sc;
    hold[i][1] = h0[(long)(nb4 + i) * 256 + jh1] * sc;
  }
  __syncthreads();

  // --- gi register prefetch: this (b, w2, c)'s chunk slice, one step ahead
  const long cstep = 128L * 8 * 384;                       // per-t chunk stride
  const __bf16* gcb = gis + ((long)b * 8 + w2) * 384 + c * 4;
  bf16x4 p00 = *(const bf16x4*)(gcb);
  bf16x4 p01 = *(const bf16x4*)(gcb + 64);
  bf16x4 p10 = *(const bf16x4*)(gcb + 128);
  bf16x4 p11 = *(const bf16x4*)(gcb + 192);
  bf16x4 pn0 = *(const bf16x4*)(gcb + 256);
  bf16x4 pn1 = *(const bf16x4*)(gcb + 320);

  const unsigned char* wrb = &wr8[w2 * 8192];   // this wave's r-W fragments

  #pragma unroll 1
  for (int t = 0; t < kT; ++t) {
    // (A) consume prefetched gi(t)
    bf16x4 q00 = p00, q01 = p01, q10 = p10, q11 = p11, qn0 = pn0, qn1 = pn1;
    unsigned du = *(const unsigned*)(&doneL[t * SQ]);

    // (B) issue gi(t+1) loads (clamped at tail)
    {
      const long tn = (t < kT - 1) ? (t + 1) : t;
      const __bf16* gc = gcb + tn * cstep;
      p00 = *(const bf16x4*)(gc);
      p01 = *(const bf16x4*)(gc + 64);
      p10 = *(const bf16x4*)(gc + 128);
      p11 = *(const bf16x4*)(gc + 192);
      pn0 = *(const bf16x4*)(gc + 256);
      pn1 = *(const bf16x4*)(gc + 320);
    }

    f32x4 ar0, ar1, az0, az1, an0, an1;
    #pragma unroll
    for (int i = 0; i < 4; ++i) {
      ar0[i] = (float)q00[i]; ar1[i] = (float)q01[i];
      az0[i] = (float)q10[i]; az1[i] = (float)q11[i];
    }
    an0 = (f32x4){bn0, bn0, bn0, bn0};
    an1 = (f32x4){bn1, bn1, bn1, bn1};
    // pin accs to ARCH VGPRs so AGPR demand stays exactly 128 (wfn+wfz)
    asm volatile("" : "+v"(ar0), "+v"(ar1), "+v"(az0), "+v"(az1), "+v"(an0), "+v"(an1));

    // (C) MFMA over K=256: A = h rows dup'd (sr); B: n,z from AGPR, r from LDS
    {
      const __bf16* hb = &hbuf[t & 1][0];
      const unsigned char* h8b = &h8buf[t & 1][0];
      #pragma unroll
      for (int ss = 0; ss < 8; ++ss) {
        int cb = (ss * 64 + lg * 16) ^ (sr << 4);
        bf16x8 afr = *(const bf16x8*)(hb + sr * 256 + (cb >> 1));
        long   a8  = *(const long*)(h8b + sr * 256 + ((ss * 32 + lg * 8) ^ (sr << 3)));
        long  br0 = *(const long*)(wrb + (ss * 64 + lane) * 8);
        long  br1 = *(const long*)(wrb + ((8 + ss) * 64 + lane) * 8);
        ar0 = __builtin_amdgcn_mfma_f32_16x16x32_fp8_fp8(a8, br0, ar0, 0, 0, 0);
        ar1 = __builtin_amdgcn_mfma_f32_16x16x32_fp8_fp8(a8, br1, ar1, 0, 0, 0);
        az0 = __builtin_amdgcn_mfma_f32_16x16x32_bf16(afr, __builtin_bit_cast(bf16x8, wfz[ss]),     az0, 0, 0, 0);
        az1 = __builtin_amdgcn_mfma_f32_16x16x32_bf16(afr, __builtin_bit_cast(bf16x8, wfz[8 + ss]), az1, 0, 0, 0);
        an0 = __builtin_amdgcn_mfma_f32_16x16x32_bf16(afr, __builtin_bit_cast(bf16x8, wfn[ss]),     an0, 0, 0, 0);
        an1 = __builtin_amdgcn_mfma_f32_16x16x32_bf16(afr, __builtin_bit_cast(bf16x8, wfn[8 + ss]), an1, 0, 0, 0);
      }
    }

    // (D) gates + update + stores (rows 0..3 real; lg==0 lanes store)
    {
      float* op = out + ((long)t * kN + nb4) * kH;
      __bf16* hw = &hbuf[(t & 1) ^ 1][0];
      unsigned char* h8w = &h8buf[(t & 1) ^ 1][0];
      #pragma unroll
      for (int i = 0; i < 4; ++i) {
        const float dn = (float)((du >> (8 * i)) & 255u);
        float r0 = sigm(ar0[i]);
        float r1 = sigm(ar1[i]);
        float z0 = sigm(az0[i]);
        float z1 = sigm(az1[i]);
        float n0v = tanh_fast((float)qn0[i] + r0 * an0[i]);
        float n1v = tanh_fast((float)qn1[i] + r1 * an1[i]);
        float hn0 = n0v + z0 * (hold[i][0] - n0v);
        float hn1 = n1v + z1 * (hold[i][1] - n1v);
        float hk0 = hn0 * (1.0f - dn);
        float hk1 = hn1 * (1.0f - dn);
        hold[i][0] = hk0;
        hold[i][1] = hk1;
        if (lg == 0) {
          op[(long)i * kH + jh0] = hn0;
          op[(long)i * kH + jh1] = hn1;
          hw[(i * 512 + ((jh0 * 2) ^ (i << 4))) >> 1] = (__bf16)hk0;
          hw[(i * 512 + ((jh1 * 2) ^ (i << 4))) >> 1] = (__bf16)hk1;
          int pk8 = __builtin_amdgcn_cvt_pk_fp8_f32(hk0, hk1, 0, 0);
          h8w[i * 256 + (jh0 ^ (i << 3))] = (unsigned char)(pk8 & 255);
          h8w[i * 256 + (jh1 ^ (i << 3))] = (unsigned char)((pk8 >> 8) & 255);
        }
      }
    }

    // (E) h(t+1) visible to all waves (simple, robust)
    __syncthreads();
  }

  // final hidden state (doneL last row = 0, so hold == h_T)
  if (lg == 0) {
    float* outF = out + (long)kT * kN * kH;
    #pragma unroll
    for (int i = 0; i < 4; ++i) {
      outF[(long)(nb4 + i) * kH + jh0] = hold[i][0];
      outF[(long)(nb4 + i) * kH + jh1] = hold[i][1];
    }
  }
}

// ---------------------------------------------------------------------------
// Fallback (ws too small): naive fp32.
// ---------------------------------------------------------------------------
__global__ __launch_bounds__(256) void gru_naive(
    const float* __restrict__ x, const float* __restrict__ h0,
    const float* __restrict__ done, const float* __restrict__ Wih,
    const float* __restrict__ Whh, const float* __restrict__ bih,
    const float* __restrict__ bhh, float* __restrict__ out)
{
  __shared__ float hsA[16][257];
  __shared__ float hsB[16][257];
  const int tid = threadIdx.x;
  const int b = blockIdx.x, nb = b * 16;
  for (int s = 0; s < 16; ++s)
    hsA[s][tid] = h0[(long)(nb + s) * 256 + tid] * (1.0f - done[nb + s]);
  __syncthreads();
  float (*hr)[257] = hsA;
  float (*hw)[257] = hsB;
  float* outF = out + (long)kT * kN * kH;
  for (int t = 0; t < kT; ++t) {
    for (int s = 0; s < 16; ++s) {
      const float* xr = x + ((long)t * kN + nb + s) * 256;
      float pr  = bih[tid] + bhh[tid];
      float pz  = bih[256 + tid] + bhh[256 + tid];
      float pnx = bih[512 + tid];
      float pnh = bhh[512 + tid];
      const float* wr = Wih + (long)tid * 256;
      const float* wz = Wih + (long)(256 + tid) * 256;
      const float* wn = Wih + (long)(512 + tid) * 256;
      const float* vr = Whh + (long)tid * 256;
      const float* vz = Whh + (long)(256 + tid) * 256;
      const float* vn = Whh + (long)(512 + tid) * 256;
      #pragma unroll 4
      for (int k = 0; k < 256; ++k) {
        float xv = xr[k], hv = hr[s][k];
        pr  = fmaf(xv, wr[k], pr);  pr  = fmaf(hv, vr[k], pr);
        pz  = fmaf(xv, wz[k], pz);  pz  = fmaf(hv, vz[k], pz);
        pnx = fmaf(xv, wn[k], pnx); pnh = fmaf(hv, vn[k], pnh);
      }
      float r = sigm(pr), z = sigm(pz);
      float n = tanh_fast(pnx + r * pnh);
      float ho = hr[s][tid];
      float hn = n + z * (ho - n);
      out[((long)t * kN + nb + s) * 256 + tid] = hn;
      if (t == kT - 1) outF[(long)(nb + s) * 256 + tid] = hn;
      float d = (t < kT - 1) ? done[(long)(t + 1) * kN + nb + s] : 0.0f;
      hw[s][tid] = hn * (1.0f - d);
    }
    __syncthreads();
    float (*tmp)[257] = hr; hr = hw; hw = tmp;
  }
}

extern "C" void kernel_launch(void* const* d_in, const int* in_sizes, int n_in,
                              void* d_out, int out_size, void* d_ws, size_t ws_size,
                              hipStream_t stream) {
  const float* x    = (const float*)d_in[0];
  const float* h0   = (const float*)d_in[1];
  const float* done = (const float*)d_in[2];
  const float* Wih  = (const float*)d_in[3];
  const float* Whh  = (const float*)d_in[4];
  const float* bih  = (const float*)d_in[5];
  const float* bhh  = (const float*)d_in[6];
  float* out = (float*)d_out;

  const size_t GI_BYTES = (size_t)kT * kN * 768 * 2;  // 402.7 MB bf16
  if (ws_size >= GI_BYTES) {
    __bf16* gis = (__bf16*)d_ws;
    hipLaunchKernelGGL(gi_gemm, dim3(2048), dim3(512), 0, stream, x, Wih, bih, bhh, gis);
    hipLaunchKernelGGL(gru_scan, dim3(SBL), dim3(512), 0, stream, gis, h0, done, Whh, bhh, out);
  } else {
    hipLaunchKernelGGL(gru_naive, dim3(32), dim3(256), 0, stream, x, h0, done, Wih, Whh, bih, bhh, out);
  }
}